// Round 13
// baseline (602.109 us; speedup 1.0000x reference)
//
#include <hip/hip_runtime.h>
#include <math.h>
#include <float.h>

#define D 256
#define NBLK 512
#define TPB 512                 // 8 waves per block
#define WPB (TPB / 64)

__device__ __forceinline__ float wave_reduce_sum(float s) {
    s += __shfl_xor(s, 32);
    s += __shfl_xor(s, 16);
    s += __shfl_xor(s, 8);
    s += __shfl_xor(s, 4);
    s += __shfl_xor(s, 2);
    s += __shfl_xor(s, 1);
    return s;
}
__device__ __forceinline__ float wave_reduce_max(float s) {
    s = fmaxf(s, __shfl_xor(s, 32));
    s = fmaxf(s, __shfl_xor(s, 16));
    s = fmaxf(s, __shfl_xor(s, 8));
    s = fmaxf(s, __shfl_xor(s, 4));
    s = fmaxf(s, __shfl_xor(s, 2));
    s = fmaxf(s, __shfl_xor(s, 1));
    return s;
}

// ---------------------------------------------------------------------------
// K0: u = B @ q ; v0 = A^T @ u ; zero the hop counters
// ---------------------------------------------------------------------------
__global__ __launch_bounds__(1024) void mr_init(const float* __restrict__ q,
                                                const float* __restrict__ Bm,
                                                const float* __restrict__ Am,
                                                float* __restrict__ u,
                                                float* __restrict__ v,
                                                int* __restrict__ cnt) {
    __shared__ __align__(16) float sq[D];
    __shared__ float su[D];
    __shared__ float part[4][D];
    const int tid = threadIdx.x;

    if (tid < 3) cnt[tid] = 0;
    if (tid < D) sq[tid] = q[tid];
    __syncthreads();
    {
        const int j = tid >> 2, qd = tid & 3;
        const float4* Br = (const float4*)(Bm + (size_t)j * D + qd * 64);
        const float4* qr = (const float4*)(sq + qd * 64);
        float acc = 0.f;
#pragma unroll
        for (int i = 0; i < 16; ++i) {
            float4 b4 = Br[i];
            float4 q4 = qr[i];
            acc += b4.x * q4.x + b4.y * q4.y + b4.z * q4.z + b4.w * q4.w;
        }
        part[qd][j] = acc;
    }
    __syncthreads();
    if (tid < D) {
        float uu = part[0][tid] + part[1][tid] + part[2][tid] + part[3][tid];
        u[tid] = uu;
        su[tid] = uu;
    }
    __syncthreads();
    {
        const int k = tid & (D - 1), h = tid >> 8;
        const int j0 = h * 64;
        float acc = 0.f;
#pragma unroll 8
        for (int jj = 0; jj < 64; ++jj)
            acc += Am[(size_t)(j0 + jj) * D + k] * su[j0 + jj];
        part[h][k] = acc;
    }
    __syncthreads();
    if (tid < D)
        v[tid] = part[0][tid] + part[1][tid] + part[2][tid] + part[3][tid];
}

// ---------------------------------------------------------------------------
// Fused pass+combine. Pass phase identical to round 12 (16-lane groups).
// After writing block partials, the LAST block (device-scope atomic counter)
// performs the global combine inline: M/Z/w reduce, o = C(w/Z), u += o,
// v_out = A^T u (or out on last hop). Other blocks exit — no spinning.
// ---------------------------------------------------------------------------
__global__ __launch_bounds__(TPB) void mr_pass_fused(
        const float* __restrict__ mem, const float* __restrict__ vin,
        float* __restrict__ vout,
        float* __restrict__ wsM, float* __restrict__ wsZ,
        float* __restrict__ wsW, int* __restrict__ cnt,
        const float* __restrict__ Cm, const float* __restrict__ Am,
        float* __restrict__ u, float* __restrict__ out,
        int nslots, int nwavesTotal, int nb, int last_hop) {
    const int tid  = threadIdx.x;
    const int lane = tid & 63;
    const int wid  = tid >> 6;
    const int l16  = lane & 15;
    const int g    = lane >> 4;
    const int gwave = blockIdx.x * WPB + wid;

    const int slab = (nslots + nwavesTotal - 1) / nwavesTotal;
    const int s0 = gwave * slab;
    const int s1 = min(s0 + slab, nslots);

    const float4 v0 = ((const float4*)vin)[l16];
    const float4 v1 = ((const float4*)vin)[l16 + 16];
    const float4 v2 = ((const float4*)vin)[l16 + 32];
    const float4 v3 = ((const float4*)vin)[l16 + 48];

    float m = -FLT_MAX, Z = 0.f;
    float4 w0 = {0,0,0,0}, w1 = {0,0,0,0}, w2 = {0,0,0,0}, w3 = {0,0,0,0};

    for (int base = s0; base < s1; base += 8) {
        const int slotA = base + g;
        const int slotB = base + 4 + g;
        const bool vA = slotA < s1;
        const bool vB = slotB < s1;
        const int cA = vA ? slotA : s0;
        const int cB = vB ? slotB : s0;
        const float4* rA = (const float4*)(mem + (size_t)cA * D);
        const float4* rB = (const float4*)(mem + (size_t)cB * D);
        float4 a0 = rA[l16], a1 = rA[l16 + 16], a2 = rA[l16 + 32], a3 = rA[l16 + 48];
        float4 b0 = rB[l16], b1 = rB[l16 + 16], b2 = rB[l16 + 32], b3 = rB[l16 + 48];

        float pA = a0.x*v0.x + a0.y*v0.y + a0.z*v0.z + a0.w*v0.w
                 + a1.x*v1.x + a1.y*v1.y + a1.z*v1.z + a1.w*v1.w
                 + a2.x*v2.x + a2.y*v2.y + a2.z*v2.z + a2.w*v2.w
                 + a3.x*v3.x + a3.y*v3.y + a3.z*v3.z + a3.w*v3.w;
        float pB = b0.x*v0.x + b0.y*v0.y + b0.z*v0.z + b0.w*v0.w
                 + b1.x*v1.x + b1.y*v1.y + b1.z*v1.z + b1.w*v1.w
                 + b2.x*v2.x + b2.y*v2.y + b2.z*v2.z + b2.w*v2.w
                 + b3.x*v3.x + b3.y*v3.y + b3.z*v3.z + b3.w*v3.w;
        pA += __shfl_xor(pA, 1);  pB += __shfl_xor(pB, 1);
        pA += __shfl_xor(pA, 2);  pB += __shfl_xor(pB, 2);
        pA += __shfl_xor(pA, 4);  pB += __shfl_xor(pB, 4);
        pA += __shfl_xor(pA, 8);  pB += __shfl_xor(pB, 8);

        {
            float sv = vA ? pA : -FLT_MAX;
            float mn = fmaxf(m, sv);
            float e  = vA ? __expf(sv - mn) : 0.f;
            if (__any(mn > m)) {
                float sc = __expf(m - mn);
                Z = Z * sc + e;
                w0.x = w0.x*sc + e*a0.x; w0.y = w0.y*sc + e*a0.y; w0.z = w0.z*sc + e*a0.z; w0.w = w0.w*sc + e*a0.w;
                w1.x = w1.x*sc + e*a1.x; w1.y = w1.y*sc + e*a1.y; w1.z = w1.z*sc + e*a1.z; w1.w = w1.w*sc + e*a1.w;
                w2.x = w2.x*sc + e*a2.x; w2.y = w2.y*sc + e*a2.y; w2.z = w2.z*sc + e*a2.z; w2.w = w2.w*sc + e*a2.w;
                w3.x = w3.x*sc + e*a3.x; w3.y = w3.y*sc + e*a3.y; w3.z = w3.z*sc + e*a3.z; w3.w = w3.w*sc + e*a3.w;
                m = mn;
            } else {
                Z += e;
                w0.x += e*a0.x; w0.y += e*a0.y; w0.z += e*a0.z; w0.w += e*a0.w;
                w1.x += e*a1.x; w1.y += e*a1.y; w1.z += e*a1.z; w1.w += e*a1.w;
                w2.x += e*a2.x; w2.y += e*a2.y; w2.z += e*a2.z; w2.w += e*a2.w;
                w3.x += e*a3.x; w3.y += e*a3.y; w3.z += e*a3.z; w3.w += e*a3.w;
            }
        }
        {
            float sv = vB ? pB : -FLT_MAX;
            float mn = fmaxf(m, sv);
            float e  = vB ? __expf(sv - mn) : 0.f;
            if (__any(mn > m)) {
                float sc = __expf(m - mn);
                Z = Z * sc + e;
                w0.x = w0.x*sc + e*b0.x; w0.y = w0.y*sc + e*b0.y; w0.z = w0.z*sc + e*b0.z; w0.w = w0.w*sc + e*b0.w;
                w1.x = w1.x*sc + e*b1.x; w1.y = w1.y*sc + e*b1.y; w1.z = w1.z*sc + e*b1.z; w1.w = w1.w*sc + e*b1.w;
                w2.x = w2.x*sc + e*b2.x; w2.y = w2.y*sc + e*b2.y; w2.z = w2.z*sc + e*b2.z; w2.w = w2.w*sc + e*b2.w;
                w3.x = w3.x*sc + e*b3.x; w3.y = w3.y*sc + e*b3.y; w3.z = w3.z*sc + e*b3.z; w3.w = w3.w*sc + e*b3.w;
                m = mn;
            } else {
                Z += e;
                w0.x += e*b0.x; w0.y += e*b0.y; w0.z += e*b0.z; w0.w += e*b0.w;
                w1.x += e*b1.x; w1.y += e*b1.y; w1.z += e*b1.z; w1.w += e*b1.w;
                w2.x += e*b2.x; w2.y += e*b2.y; w2.z += e*b2.z; w2.w += e*b2.w;
                w3.x += e*b3.x; w3.y += e*b3.y; w3.z += e*b3.z; w3.w += e*b3.w;
            }
        }
    }

    // ---- block combine: 8 waves x 4 groups = 32 partials ----
    __shared__ __align__(16) float lw[WPB * 4][D];
    __shared__ float lm[WPB * 4];
    __shared__ float lz[WPB * 4];
    __shared__ float lf[WPB * 4];
    const int grp = wid * 4 + g;
    *(float4*)&lw[grp][(l16 +  0) * 4] = w0;
    *(float4*)&lw[grp][(l16 + 16) * 4] = w1;
    *(float4*)&lw[grp][(l16 + 32) * 4] = w2;
    *(float4*)&lw[grp][(l16 + 48) * 4] = w3;
    if (l16 == 0) { lm[grp] = m; lz[grp] = Z; }
    __syncthreads();

    if (tid < 32) {
        float mm = lm[tid];
        float M = mm;
        M = fmaxf(M, __shfl_xor(M, 1));
        M = fmaxf(M, __shfl_xor(M, 2));
        M = fmaxf(M, __shfl_xor(M, 4));
        M = fmaxf(M, __shfl_xor(M, 8));
        M = fmaxf(M, __shfl_xor(M, 16));
        float fv = __expf(mm - M);
        lf[tid] = fv;
        float zf = lz[tid] * fv;
        zf += __shfl_xor(zf, 1);
        zf += __shfl_xor(zf, 2);
        zf += __shfl_xor(zf, 4);
        zf += __shfl_xor(zf, 8);
        zf += __shfl_xor(zf, 16);
        if (tid == 0) { wsM[blockIdx.x] = M; wsZ[blockIdx.x] = zf; }
    }
    __syncthreads();

    if (tid < D) {
        float wacc = 0.f;
#pragma unroll
        for (int p = 0; p < WPB * 4; ++p) wacc += lw[p][tid] * lf[p];
        wsW[(size_t)blockIdx.x * D + tid] = wacc;
    }

    // ---- last-block global combine ----
    __shared__ int sLast;
    __threadfence();                       // partials visible device-wide
    __syncthreads();                       // all writes in this block done
    if (tid == 0)
        sLast = (atomicAdd(cnt, 1) == nb - 1) ? 1 : 0;
    __syncthreads();
    if (!sLast) return;
    __threadfence();                       // acquire: see all blocks' partials

    __shared__ float f[NBLK];
    __shared__ float red[WPB];
    __shared__ float sMZ[2];
    __shared__ __align__(16) float part2[2][D];
    __shared__ __align__(16) float sw[D];
    __shared__ float su[D];

    // Phase A: global max
    float lmx = -FLT_MAX;
    for (int b = tid; b < nb; b += TPB) lmx = fmaxf(lmx, wsM[b]);
    lmx = wave_reduce_max(lmx);
    if (lane == 0) red[wid] = lmx;
    __syncthreads();
    if (tid == 0) {
        float M = red[0];
#pragma unroll
        for (int i = 1; i < WPB; ++i) M = fmaxf(M, red[i]);
        sMZ[0] = M;
    }
    __syncthreads();
    const float M = sMZ[0];

    // Phase A2: f[b], Z
    float zp = 0.f;
    for (int b = tid; b < nb; b += TPB) {
        float fb = __expf(wsM[b] - M);
        f[b] = fb;
        zp += wsZ[b] * fb;
    }
    zp = wave_reduce_sum(zp);
    if (lane == 0) red[wid] = zp;
    __syncthreads();
    if (tid == 0) {
        float Zs = 0.f;
#pragma unroll
        for (int i = 0; i < WPB; ++i) Zs += red[i];
        sMZ[1] = Zs;
    }
    __syncthreads();
    const float Zt = sMZ[1];

    // Phase B: w_c = sum_b wsW[b][c] f[b]  (2 chunks x 256 components)
    {
        const int c = tid & (D - 1);
        const int chunk = tid >> 8;            // 0..1
        const int bpc = nb >> 1;
        const int b0 = chunk * bpc, b1 = b0 + bpc;
        float acc = 0.f;
#pragma unroll 8
        for (int b = b0; b < b1; ++b)
            acc += wsW[(size_t)b * D + c] * f[b];
        part2[chunk][c] = acc;
    }
    __syncthreads();
    if (tid < D)
        sw[tid] = (part2[0][tid] + part2[1][tid]) / Zt;
    __syncthreads();

    // Phase C: o_j = sum_k C[j,k] sw[k]  (half-split rows, 512 threads)
    {
        const int j = tid >> 1, h2 = tid & 1;
        const float4* Cr = (const float4*)(Cm + (size_t)j * D + h2 * 128);
        const float4* wr = (const float4*)(sw + h2 * 128);
        float acc = 0.f;
#pragma unroll
        for (int i = 0; i < 32; ++i) {
            float4 c4 = Cr[i];
            float4 w4 = wr[i];
            acc += c4.x * w4.x + c4.y * w4.y + c4.z * w4.z + c4.w * w4.w;
        }
        __syncthreads();                   // part2 reuse
        part2[h2][j] = acc;
    }
    __syncthreads();
    if (tid < D) {
        float o = part2[0][tid] + part2[1][tid];
        float un = u[tid] + o;
        u[tid] = un;
        su[tid] = un;
        if (last_hop) out[tid] = un;
    }
    __syncthreads();

    if (!last_hop) {
        // v_out_k = sum_j A[j,k] u_j  (coalesced across k, half-split over j)
        const int k = tid & (D - 1), h = tid >> 8;
        const int j0 = h * 128;
        float acc = 0.f;
#pragma unroll 8
        for (int jj = 0; jj < 128; ++jj)
            acc += Am[(size_t)(j0 + jj) * D + k] * su[j0 + jj];
        __syncthreads();                   // part2 reuse
        part2[h][k] = acc;
        __syncthreads();
        if (tid < D)
            vout[tid] = part2[0][tid] + part2[1][tid];
    }
}

// ---------------------------------------------------------------------------
extern "C" void kernel_launch(void* const* d_in, const int* in_sizes, int n_in,
                              void* d_out, int out_size, void* d_ws, size_t ws_size,
                              hipStream_t stream) {
    const float* mem = (const float*)d_in[0];
    const float* q   = (const float*)d_in[1];
    const float* A   = (const float*)d_in[2];
    const float* B   = (const float*)d_in[3];
    const float* C   = (const float*)d_in[4];
    float* out = (float*)d_out;
    float* ws  = (float*)d_ws;

    const int nslots = in_sizes[0] / D;

    // ws layout (floats): u[256] | v0 v1 v2 [256 each] | cnt (3 ints, 4 slots)
    //                     | wsM[nb] | wsZ[nb] | wsW[nb*256]
    long wsf = (long)(ws_size / 4);
    int nb = NBLK;
    long fixed = 4L * D + 4;
    long need = fixed + (long)nb * (2 + D);
    if (need > wsf) {
        nb = (int)((wsf - fixed) / (2 + D));
        nb &= ~1;
        if (nb < 2) nb = 2;
    }

    float* u   = ws;
    float* v0  = ws + D;
    float* v1  = ws + 2 * D;
    float* v2  = ws + 3 * D;
    int*   cnt = (int*)(ws + 4 * D);
    float* wsM = ws + 4 * D + 4;
    float* wsZ = wsM + nb;
    float* wsW = wsZ + nb;

    float* vin[3]  = {v0, v1, v2};
    float* vout[3] = {v1, v2, v0};   // last hop's vout unused

    mr_init<<<1, 1024, 0, stream>>>(q, B, A, u, v0, cnt);
    for (int hop = 0; hop < 3; ++hop) {
        mr_pass_fused<<<nb, TPB, 0, stream>>>(
            mem, vin[hop], vout[hop], wsM, wsZ, wsW, cnt + hop,
            C, A, u, out, nslots, nb * WPB, nb, hop == 2 ? 1 : 0);
    }
}

// Round 14
// 263.673 us; speedup vs baseline: 2.2835x; 2.2835x over previous
//
#include <hip/hip_runtime.h>
#include <math.h>
#include <float.h>

#define D 256
#define NB 1024                 // pass blocks
#define TPB 512                 // 8 waves per block
#define WPB (TPB / 64)
#define C2B 64                  // combine stage-2 blocks

__device__ __forceinline__ float wave_reduce_sum(float s) {
    s += __shfl_xor(s, 32);
    s += __shfl_xor(s, 16);
    s += __shfl_xor(s, 8);
    s += __shfl_xor(s, 4);
    s += __shfl_xor(s, 2);
    s += __shfl_xor(s, 1);
    return s;
}
__device__ __forceinline__ float wave_reduce_max(float s) {
    s = fmaxf(s, __shfl_xor(s, 32));
    s = fmaxf(s, __shfl_xor(s, 16));
    s = fmaxf(s, __shfl_xor(s, 8));
    s = fmaxf(s, __shfl_xor(s, 4));
    s = fmaxf(s, __shfl_xor(s, 2));
    s = fmaxf(s, __shfl_xor(s, 1));
    return s;
}

// ---------------------------------------------------------------------------
// K0: u = B @ q ; vp0[4][256] = partial A^T u (4 j-quarters, summed in pass)
// ---------------------------------------------------------------------------
__global__ __launch_bounds__(1024) void mr_init(const float* __restrict__ q,
                                                const float* __restrict__ Bm,
                                                const float* __restrict__ Am,
                                                float* __restrict__ u,
                                                float* __restrict__ vp0) {
    __shared__ __align__(16) float sq[D];
    __shared__ float su[D];
    __shared__ float part[4][D];
    const int tid = threadIdx.x;

    if (tid < D) sq[tid] = q[tid];
    __syncthreads();
    {
        const int j = tid >> 2, qd = tid & 3;
        const float4* Br = (const float4*)(Bm + (size_t)j * D + qd * 64);
        const float4* qr = (const float4*)(sq + qd * 64);
        float acc = 0.f;
#pragma unroll
        for (int i = 0; i < 16; ++i) {
            float4 b4 = Br[i];
            float4 q4 = qr[i];
            acc += b4.x * q4.x + b4.y * q4.y + b4.z * q4.z + b4.w * q4.w;
        }
        part[qd][j] = acc;
    }
    __syncthreads();
    if (tid < D) {
        float uu = part[0][tid] + part[1][tid] + part[2][tid] + part[3][tid];
        u[tid] = uu;
        su[tid] = uu;
    }
    __syncthreads();
    {
        const int k = tid & (D - 1), h = tid >> 8;   // h = j-quarter
        const int j0 = h * 64;
        float acc = 0.f;
#pragma unroll 8
        for (int jj = 0; jj < 64; ++jj)
            acc += Am[(size_t)(j0 + jj) * D + k] * su[j0 + jj];
        vp0[h * D + k] = acc;                        // partial, not summed
    }
}

// ---------------------------------------------------------------------------
// Pass (round-12 body). v input arrives as 4 partials, summed in prologue.
// ---------------------------------------------------------------------------
__global__ __launch_bounds__(TPB) void mr_pass(
        const float* __restrict__ mem, const float* __restrict__ vp,
        float* __restrict__ wsM, float* __restrict__ wsZ,
        float* __restrict__ wsW, int nslots, int nwavesTotal) {
    const int tid  = threadIdx.x;
    const int lane = tid & 63;
    const int wid  = tid >> 6;
    const int l16  = lane & 15;
    const int g    = lane >> 4;
    const int gwave = blockIdx.x * WPB + wid;

    const int slab = (nslots + nwavesTotal - 1) / nwavesTotal;
    const int s0 = gwave * slab;
    const int s1 = min(s0 + slab, nslots);

    const float4* vp4 = (const float4*)vp;           // [4][64] float4
    float4 v0, v1, v2, v3;
    {
        float4 p0, p1, p2, p3;
#define SUM4(dst, i)                                                          \
        p0 = vp4[(i)];        p1 = vp4[64 + (i)];                             \
        p2 = vp4[128 + (i)];  p3 = vp4[192 + (i)];                            \
        dst.x = p0.x + p1.x + p2.x + p3.x;                                    \
        dst.y = p0.y + p1.y + p2.y + p3.y;                                    \
        dst.z = p0.z + p1.z + p2.z + p3.z;                                    \
        dst.w = p0.w + p1.w + p2.w + p3.w;
        SUM4(v0, l16);
        SUM4(v1, l16 + 16);
        SUM4(v2, l16 + 32);
        SUM4(v3, l16 + 48);
#undef SUM4
    }

    float m = -FLT_MAX, Z = 0.f;
    float4 w0 = {0,0,0,0}, w1 = {0,0,0,0}, w2 = {0,0,0,0}, w3 = {0,0,0,0};

    for (int base = s0; base < s1; base += 8) {
        const int slotA = base + g;
        const int slotB = base + 4 + g;
        const bool vA = slotA < s1;
        const bool vB = slotB < s1;
        const int cA = vA ? slotA : s0;
        const int cB = vB ? slotB : s0;
        const float4* rA = (const float4*)(mem + (size_t)cA * D);
        const float4* rB = (const float4*)(mem + (size_t)cB * D);
        float4 a0 = rA[l16], a1 = rA[l16 + 16], a2 = rA[l16 + 32], a3 = rA[l16 + 48];
        float4 b0 = rB[l16], b1 = rB[l16 + 16], b2 = rB[l16 + 32], b3 = rB[l16 + 48];

        float pA = a0.x*v0.x + a0.y*v0.y + a0.z*v0.z + a0.w*v0.w
                 + a1.x*v1.x + a1.y*v1.y + a1.z*v1.z + a1.w*v1.w
                 + a2.x*v2.x + a2.y*v2.y + a2.z*v2.z + a2.w*v2.w
                 + a3.x*v3.x + a3.y*v3.y + a3.z*v3.z + a3.w*v3.w;
        float pB = b0.x*v0.x + b0.y*v0.y + b0.z*v0.z + b0.w*v0.w
                 + b1.x*v1.x + b1.y*v1.y + b1.z*v1.z + b1.w*v1.w
                 + b2.x*v2.x + b2.y*v2.y + b2.z*v2.z + b2.w*v2.w
                 + b3.x*v3.x + b3.y*v3.y + b3.z*v3.z + b3.w*v3.w;
        pA += __shfl_xor(pA, 1);  pB += __shfl_xor(pB, 1);
        pA += __shfl_xor(pA, 2);  pB += __shfl_xor(pB, 2);
        pA += __shfl_xor(pA, 4);  pB += __shfl_xor(pB, 4);
        pA += __shfl_xor(pA, 8);  pB += __shfl_xor(pB, 8);

        {
            float sv = vA ? pA : -FLT_MAX;
            float mn = fmaxf(m, sv);
            float e  = vA ? __expf(sv - mn) : 0.f;
            if (__any(mn > m)) {
                float sc = __expf(m - mn);
                Z = Z * sc + e;
                w0.x = w0.x*sc + e*a0.x; w0.y = w0.y*sc + e*a0.y; w0.z = w0.z*sc + e*a0.z; w0.w = w0.w*sc + e*a0.w;
                w1.x = w1.x*sc + e*a1.x; w1.y = w1.y*sc + e*a1.y; w1.z = w1.z*sc + e*a1.z; w1.w = w1.w*sc + e*a1.w;
                w2.x = w2.x*sc + e*a2.x; w2.y = w2.y*sc + e*a2.y; w2.z = w2.z*sc + e*a2.z; w2.w = w2.w*sc + e*a2.w;
                w3.x = w3.x*sc + e*a3.x; w3.y = w3.y*sc + e*a3.y; w3.z = w3.z*sc + e*a3.z; w3.w = w3.w*sc + e*a3.w;
                m = mn;
            } else {
                Z += e;
                w0.x += e*a0.x; w0.y += e*a0.y; w0.z += e*a0.z; w0.w += e*a0.w;
                w1.x += e*a1.x; w1.y += e*a1.y; w1.z += e*a1.z; w1.w += e*a1.w;
                w2.x += e*a2.x; w2.y += e*a2.y; w2.z += e*a2.z; w2.w += e*a2.w;
                w3.x += e*a3.x; w3.y += e*a3.y; w3.z += e*a3.z; w3.w += e*a3.w;
            }
        }
        {
            float sv = vB ? pB : -FLT_MAX;
            float mn = fmaxf(m, sv);
            float e  = vB ? __expf(sv - mn) : 0.f;
            if (__any(mn > m)) {
                float sc = __expf(m - mn);
                Z = Z * sc + e;
                w0.x = w0.x*sc + e*b0.x; w0.y = w0.y*sc + e*b0.y; w0.z = w0.z*sc + e*b0.z; w0.w = w0.w*sc + e*b0.w;
                w1.x = w1.x*sc + e*b1.x; w1.y = w1.y*sc + e*b1.y; w1.z = w1.z*sc + e*b1.z; w1.w = w1.w*sc + e*b1.w;
                w2.x = w2.x*sc + e*b2.x; w2.y = w2.y*sc + e*b2.y; w2.z = w2.z*sc + e*b2.z; w2.w = w2.w*sc + e*b2.w;
                w3.x = w3.x*sc + e*b3.x; w3.y = w3.y*sc + e*b3.y; w3.z = w3.z*sc + e*b3.z; w3.w = w3.w*sc + e*b3.w;
                m = mn;
            } else {
                Z += e;
                w0.x += e*b0.x; w0.y += e*b0.y; w0.z += e*b0.z; w0.w += e*b0.w;
                w1.x += e*b1.x; w1.y += e*b1.y; w1.z += e*b1.z; w1.w += e*b1.w;
                w2.x += e*b2.x; w2.y += e*b2.y; w2.z += e*b2.z; w2.w += e*b2.w;
                w3.x += e*b3.x; w3.y += e*b3.y; w3.z += e*b3.z; w3.w += e*b3.w;
            }
        }
    }

    // ---- block combine: 8 waves x 4 groups = 32 partials ----
    __shared__ __align__(16) float lw[WPB * 4][D];
    __shared__ float lm[WPB * 4];
    __shared__ float lz[WPB * 4];
    __shared__ float lf[WPB * 4];
    const int grp = wid * 4 + g;
    *(float4*)&lw[grp][(l16 +  0) * 4] = w0;
    *(float4*)&lw[grp][(l16 + 16) * 4] = w1;
    *(float4*)&lw[grp][(l16 + 32) * 4] = w2;
    *(float4*)&lw[grp][(l16 + 48) * 4] = w3;
    if (l16 == 0) { lm[grp] = m; lz[grp] = Z; }
    __syncthreads();

    if (tid < 32) {
        float mm = lm[tid];
        float M = mm;
        M = fmaxf(M, __shfl_xor(M, 1));
        M = fmaxf(M, __shfl_xor(M, 2));
        M = fmaxf(M, __shfl_xor(M, 4));
        M = fmaxf(M, __shfl_xor(M, 8));
        M = fmaxf(M, __shfl_xor(M, 16));
        float fv = __expf(mm - M);
        lf[tid] = fv;
        float zf = lz[tid] * fv;
        zf += __shfl_xor(zf, 1);
        zf += __shfl_xor(zf, 2);
        zf += __shfl_xor(zf, 4);
        zf += __shfl_xor(zf, 8);
        zf += __shfl_xor(zf, 16);
        if (tid == 0) { wsM[blockIdx.x] = M; wsZ[blockIdx.x] = zf; }
    }
    __syncthreads();

    if (tid < D) {
        float wacc = 0.f;
#pragma unroll
        for (int p = 0; p < WPB * 4; ++p) wacc += lw[p][tid] * lf[p];
        wsW[(size_t)blockIdx.x * D + tid] = wacc;
    }
}

// ---------------------------------------------------------------------------
// C2: 64 blocks x 256 thr. Each block: cheap global-M reduce (4 KB), then
// partial w over its nb/64 rows -> w_part[block][256].
// ---------------------------------------------------------------------------
__global__ __launch_bounds__(256) void mr_c2(const float* __restrict__ wsM,
                                             const float* __restrict__ wsW,
                                             float* __restrict__ w_part,
                                             int nb) {
    __shared__ float red[4];
    __shared__ float sM;
    const int tid = threadIdx.x;
    const int lane = tid & 63, wv = tid >> 6;

    float lm = -FLT_MAX;
    for (int b = tid; b < nb; b += 256) lm = fmaxf(lm, wsM[b]);
    lm = wave_reduce_max(lm);
    if (lane == 0) red[wv] = lm;
    __syncthreads();
    if (tid == 0)
        sM = fmaxf(fmaxf(red[0], red[1]), fmaxf(red[2], red[3]));
    __syncthreads();
    const float M = sM;

    const int rpb = nb / C2B;
    const int b0 = blockIdx.x * rpb;
    float acc = 0.f;
    for (int bb = 0; bb < rpb; ++bb) {
        float fb = __expf(wsM[b0 + bb] - M);
        acc += wsW[(size_t)(b0 + bb) * D + tid] * fb;
    }
    w_part[blockIdx.x * D + tid] = acc;
}

// ---------------------------------------------------------------------------
// C3a: 4 blocks x 256 thr. Each block: M,Z reduce (8 KB), w = sum w_part,
// o_j = C[j,:]·(w/Z) for its 64 rows, u[j] += o_j (and out on last hop).
// ---------------------------------------------------------------------------
__global__ __launch_bounds__(256) void mr_c3a(const float* __restrict__ wsM,
                                              const float* __restrict__ wsZ,
                                              const float* __restrict__ w_part,
                                              const float* __restrict__ Cm,
                                              float* __restrict__ u,
                                              float* __restrict__ out,
                                              int nb, int last) {
    __shared__ float red[4];
    __shared__ float sMZ[2];
    __shared__ __align__(16) float sw[D];
    __shared__ float part[4][64];
    const int tid = threadIdx.x;
    const int lane = tid & 63, wv = tid >> 6;

    float lm = -FLT_MAX;
    for (int b = tid; b < nb; b += 256) lm = fmaxf(lm, wsM[b]);
    lm = wave_reduce_max(lm);
    if (lane == 0) red[wv] = lm;
    __syncthreads();
    if (tid == 0)
        sMZ[0] = fmaxf(fmaxf(red[0], red[1]), fmaxf(red[2], red[3]));
    __syncthreads();
    const float M = sMZ[0];

    float zp = 0.f;
    for (int b = tid; b < nb; b += 256) zp += wsZ[b] * __expf(wsM[b] - M);
    zp = wave_reduce_sum(zp);
    if (lane == 0) red[wv] = zp;
    __syncthreads();
    if (tid == 0) sMZ[1] = red[0] + red[1] + red[2] + red[3];
    __syncthreads();
    const float Z = sMZ[1];

    // w[c] = sum over 64 partials (coalesced rows)
    {
        float acc = 0.f;
#pragma unroll 8
        for (int p = 0; p < C2B; ++p)
            acc += w_part[p * D + tid];
        sw[tid] = acc / Z;
    }
    __syncthreads();

    // o for this block's 64 rows: 4 threads per row
    const int jloc = tid >> 2, qd = tid & 3;
    const int j = blockIdx.x * 64 + jloc;
    {
        const float4* Cr = (const float4*)(Cm + (size_t)j * D + qd * 64);
        const float4* wr = (const float4*)(sw + qd * 64);
        float acc = 0.f;
#pragma unroll
        for (int i = 0; i < 16; ++i) {
            float4 c4 = Cr[i];
            float4 w4 = wr[i];
            acc += c4.x * w4.x + c4.y * w4.y + c4.z * w4.z + c4.w * w4.w;
        }
        part[qd][jloc] = acc;
    }
    __syncthreads();
    if (tid < 64) {
        const int jg = blockIdx.x * 64 + tid;
        float o = part[0][tid] + part[1][tid] + part[2][tid] + part[3][tid];
        float un = u[jg] + o;
        u[jg] = un;
        if (last) out[jg] = un;
    }
}

// ---------------------------------------------------------------------------
// C3b: 4 blocks x 256 thr. Block h: vp_next[h][k] = sum_{j in h-quarter}
// A[j,k] * u[j]  (partials summed in next pass's prologue).
// ---------------------------------------------------------------------------
__global__ __launch_bounds__(256) void mr_c3b(const float* __restrict__ Am,
                                              const float* __restrict__ u,
                                              float* __restrict__ vp_next) {
    __shared__ float su[64];
    const int tid = threadIdx.x;
    const int j0 = blockIdx.x * 64;
    if (tid < 64) su[tid] = u[j0 + tid];
    __syncthreads();
    float acc = 0.f;
#pragma unroll 8
    for (int jj = 0; jj < 64; ++jj)
        acc += Am[(size_t)(j0 + jj) * D + tid] * su[jj];
    vp_next[blockIdx.x * D + tid] = acc;
}

// ---------------------------------------------------------------------------
extern "C" void kernel_launch(void* const* d_in, const int* in_sizes, int n_in,
                              void* d_out, int out_size, void* d_ws, size_t ws_size,
                              hipStream_t stream) {
    const float* mem = (const float*)d_in[0];
    const float* q   = (const float*)d_in[1];
    const float* A   = (const float*)d_in[2];
    const float* B   = (const float*)d_in[3];
    const float* C   = (const float*)d_in[4];
    float* out = (float*)d_out;
    float* ws  = (float*)d_ws;

    const int nslots = in_sizes[0] / D;

    // ws layout (floats): u[256] | vp0,vp1,vp2 [4*256 each] | wsM[nb] | wsZ[nb]
    //                     | wsW[nb*256] | w_part[64*256]
    long wsf = (long)(ws_size / 4);
    int nb = NB;
    long fixed = 256L + 3 * 4 * 256 + (long)C2B * D;
    long need = fixed + (long)nb * (2 + D);
    if (need > wsf) {
        nb = (int)((wsf - fixed) / (2 + D));
        nb &= ~(C2B - 1);
        if (nb < C2B) nb = C2B;
    }

    float* u      = ws;
    float* vp0    = ws + 256;
    float* vp1    = vp0 + 4 * 256;
    float* vp2    = vp1 + 4 * 256;
    float* w_part = vp2 + 4 * 256;
    float* wsM    = w_part + C2B * D;
    float* wsZ    = wsM + nb;
    float* wsW    = wsZ + nb;

    float* vin[3]  = {vp0, vp1, vp2};
    float* vnx[3]  = {vp1, vp2, vp0};   // last hop's unused

    mr_init<<<1, 1024, 0, stream>>>(q, B, A, u, vp0);
    for (int hop = 0; hop < 3; ++hop) {
        const int last = (hop == 2) ? 1 : 0;
        mr_pass<<<nb, TPB, 0, stream>>>(mem, vin[hop], wsM, wsZ, wsW,
                                        nslots, nb * WPB);
        mr_c2<<<C2B, 256, 0, stream>>>(wsM, wsW, w_part, nb);
        mr_c3a<<<4, 256, 0, stream>>>(wsM, wsZ, w_part, C, u, out, nb, last);
        if (!last)
            mr_c3b<<<4, 256, 0, stream>>>(A, u, vnx[hop]);
    }
}